// Round 1
// baseline (2702.498 us; speedup 1.0000x reference)
//
#include <hip/hip_runtime.h>

// Problem: DIMS=256, T=1024, N=64 -> ROWS=65536 ; M=64 memory slots.
// query:  (256, 1024, 64) fp32  -> qr[row,d] = query[d*65536 + row]
// keys:   (64, 256) fp32
// Outputs (concat, fp32):
//  out0 updated_query (512,1024,64) : c<256 -> copy of query ; c>=256 -> (score_memory@keys)^T
//  out1 updated_memory (64,256)
//  out2 score_query   (65536,64)
//  out3 score_memory  (65536,64)
//  out4 spreading_loss(65536,)
//  out5 gathering_loss(65536,256)

#define ROWS 65536
#define EPS_T 1e-6f

// workspace layout (float offsets)
#define WS_SCORE   0          // 65536*64
#define WS_KEYST   4194304    // 256*64 (keys transposed, [d][m])
#define WS_COLMAX  4210688    // 64 (monotone-uint mapped)
#define WS_COLSUM  4210752    // 64
#define WS_QU      4210816    // 64*256
#define WS_GIDX    4227200    // 65536 int
#define WS_NIDX    4292736    // 65536 int

// output layout (float offsets)
#define O_UQ   0
#define O_UM   33554432
#define O_SQ   33570816
#define O_SM   37765120
#define O_SPR  41959424
#define O_GL   42024960

__device__ __forceinline__ unsigned fmap(float v){
  unsigned b = __float_as_uint(v);
  return (b & 0x80000000u) ? ~b : (b | 0x80000000u);   // order-preserving float->uint
}
__device__ __forceinline__ float funmap(unsigned u){
  unsigned b = (u & 0x80000000u) ? (u ^ 0x80000000u) : ~u;
  return __uint_as_float(b);
}

__global__ void k_init(float* p, int n){
  int i = blockIdx.x*256 + threadIdx.x;
  if (i < n) p[i] = 0.f;           // zero bits == 0u sentinel for colmax (-inf under fmap)
}

// keysT[d*64+m] = keys[m*256+d]
__global__ void k_transpose(const float* __restrict__ keys, float* __restrict__ kT){
  int idx = blockIdx.x*256 + threadIdx.x;
  int g = idx & 63, d = idx >> 6;
  kT[d*64 + g] = keys[g*256 + d];
}

// One thread per row: full 64-wide score row in registers.
// Writes raw score (ws), score_memory (out3), top-2 indices.
__global__ void __launch_bounds__(256) k_score(const float* __restrict__ q,
        const float* __restrict__ kT, float* __restrict__ score,
        float* __restrict__ out_sm, int* __restrict__ gidx, int* __restrict__ nidx){
  int r = blockIdx.x*256 + threadIdx.x;
  float acc[64];
  #pragma unroll
  for (int m=0;m<64;m++) acc[m]=0.f;
  #pragma unroll 2
  for (int d=0; d<256; d++){
    float qv = q[(size_t)d*ROWS + r];        // coalesced (lane = r)
    const float* kc = kT + d*64;             // wave-uniform -> scalar loads
    #pragma unroll
    for (int m=0;m<64;m++) acc[m] = fmaf(qv, kc[m], acc[m]);
  }
  // top-2 (first index wins on ties, matching lax.top_k)
  float v1=-3.4e38f, v2=-3.4e38f; int i1=0, i2=0;
  #pragma unroll
  for (int m=0;m<64;m++){
    float v=acc[m];
    if (v > v1){ v2=v1; i2=i1; v1=v; i1=m; }
    else if (v > v2){ v2=v; i2=m; }
  }
  gidx[r]=i1; nidx[r]=i2;
  float4* sp = (float4*)(score + (size_t)r*64);
  #pragma unroll
  for (int t=0;t<16;t++) sp[t] = make_float4(acc[4*t],acc[4*t+1],acc[4*t+2],acc[4*t+3]);
  // row softmax
  float s=0.f;
  #pragma unroll
  for (int m=0;m<64;m++){ acc[m]=__expf(acc[m]-v1); s+=acc[m]; }
  float inv = 1.f/s;
  float4* mp = (float4*)(out_sm + (size_t)r*64);
  #pragma unroll
  for (int t=0;t<16;t++) mp[t]=make_float4(acc[4*t]*inv,acc[4*t+1]*inv,acc[4*t+2]*inv,acc[4*t+3]*inv);
}

// column max over 65536 rows (pass 1 of column softmax)
__global__ void k_colmax(const float* __restrict__ score, unsigned* __restrict__ colmax){
  __shared__ float red[256];
  int m = threadIdx.x & 63, sub = threadIdx.x >> 6;
  int r0 = blockIdx.x*256 + sub*64;
  float v = -3.4e38f;
  for (int i=0;i<64;i++) v = fmaxf(v, score[(size_t)(r0+i)*64 + m]);
  red[threadIdx.x]=v; __syncthreads();
  if (threadIdx.x < 64){
    float a = fmaxf(fmaxf(red[m],red[64+m]),fmaxf(red[128+m],red[192+m]));
    atomicMax(&colmax[m], fmap(a));
  }
}

// column sum of exp (pass 2)
__global__ void k_colsum(const float* __restrict__ score, const unsigned* __restrict__ colmax,
                         float* __restrict__ colsum){
  __shared__ float red[256];
  int m = threadIdx.x & 63, sub = threadIdx.x >> 6;
  int r0 = blockIdx.x*256 + sub*64;
  float cm = funmap(colmax[m]);
  float v=0.f;
  for (int i=0;i<64;i++) v += __expf(score[(size_t)(r0+i)*64 + m] - cm);
  red[threadIdx.x]=v; __syncthreads();
  if (threadIdx.x<64){
    atomicAdd(&colsum[m], red[m]+red[64+m]+red[128+m]+red[192+m]);
  }
}

// score_query output + weights + scatter of query_update.
// weights[r,g] = exp(score[r,g]-colmax[g])  (== score_query/col_max analytically)
__global__ void __launch_bounds__(256) k_sq_scatter(const float* __restrict__ score,
        const unsigned* __restrict__ colmax, const float* __restrict__ colsum,
        const int* __restrict__ gidx, const float* __restrict__ q,
        float* __restrict__ out_sq, float* __restrict__ qu){
  int r = blockIdx.x*256 + threadIdx.x;
  float s[64];
  const float4* sp = (const float4*)(score + (size_t)r*64);
  #pragma unroll
  for (int t=0;t<16;t++){ float4 v=sp[t]; s[4*t]=v.x; s[4*t+1]=v.y; s[4*t+2]=v.z; s[4*t+3]=v.w; }
  int g = gidx[r];
  float w = 0.f;
  float4* op = (float4*)(out_sq + (size_t)r*64);
  #pragma unroll
  for (int t=0;t<16;t++){
    float4 o;
    #pragma unroll
    for (int j=0;j<4;j++){
      int m=4*t+j;
      float e = __expf(s[m] - funmap(colmax[m]));
      if (m==g) w=e;
      (&o.x)[j] = e / colsum[m];
    }
    op[t]=o;
  }
  float* dst = qu + g*256;
  #pragma unroll 4
  for (int d=0; d<256; d++)
    atomicAdd(dst + d, w * q[(size_t)d*ROWS + r]);   // coalesced read, contended atomic
}

// updated_memory = l2norm(query_update + keys), one block per slot
__global__ void k_upmem(const float* __restrict__ qu, const float* __restrict__ keys,
                        float* __restrict__ out_um){
  __shared__ float red[4];
  int j = blockIdx.x, t = threadIdx.x;
  float x = qu[j*256+t] + keys[j*256+t];
  float ss = x*x;
  #pragma unroll
  for (int o=32;o>0;o>>=1) ss += __shfl_down(ss, o, 64);
  if ((t & 63)==0) red[t>>6]=ss;
  __syncthreads();
  float tot = red[0]+red[1]+red[2]+red[3];
  float nrm = sqrtf(tot);
  out_um[j*256+t] = x / fmaxf(nrm, 1e-12f);
}

// second half of updated_query: (score_memory @ keys) stored channel-major
__global__ void __launch_bounds__(256) k_concat(const float* __restrict__ sm,
        const float* __restrict__ kT, float* __restrict__ out_uq){
  int r = blockIdx.x*256 + threadIdx.x;
  float v[64];
  const float4* sp = (const float4*)(sm + (size_t)r*64);
  #pragma unroll
  for (int t=0;t<16;t++){ float4 x=sp[t]; v[4*t]=x.x; v[4*t+1]=x.y; v[4*t+2]=x.z; v[4*t+3]=x.w; }
  float* dst = out_uq + (size_t)256*ROWS + r;
  #pragma unroll 2
  for (int d=0; d<256; d++){
    const float* kc = kT + d*64;    // uniform -> scalar
    float a=0.f;
    #pragma unroll
    for (int m=0;m<64;m++) a = fmaf(v[m], kc[m], a);
    dst[(size_t)d*ROWS] = a;        // coalesced
  }
}

// query copy into out0 + gathering_loss + spreading_loss
__global__ void __launch_bounds__(256) k_copy_gather(const float* __restrict__ q,
        const float* __restrict__ keys, const int* __restrict__ gidx, const int* __restrict__ nidx,
        float* __restrict__ out_uq, float* __restrict__ out_spr, float* __restrict__ out_gl){
  __shared__ float KT[256*64];      // KT[d][g] : fixed d, varying g -> conflict-free
  for (int idx=threadIdx.x; idx<16384; idx+=256){
    int g = idx & 63, d = idx >> 6;
    KT[d*64+g] = keys[g*256+d];
  }
  __syncthreads();
  int r = blockIdx.x*256 + threadIdx.x;
  int g = gidx[r], n2 = nidx[r];
  float dp=0.f, dn=0.f;
  for (int d0=0; d0<256; d0+=4){
    float4 gl;
    #pragma unroll
    for (int i=0;i<4;i++){
      int d=d0+i;
      float qv = q[(size_t)d*ROWS + r];
      out_uq[(size_t)d*ROWS + r] = qv;          // first-half copy
      float kp = KT[d*64+g];
      float kn = KT[d*64+n2];
      float cp = qv - kp, cn = qv - kn;
      (&gl.x)[i] = cp*cp;
      float a = cp + EPS_T, b = cn + EPS_T;
      dp = fmaf(a,a,dp); dn = fmaf(b,b,dn);
    }
    *(float4*)(out_gl + (size_t)r*256 + d0) = gl;
  }
  out_spr[r] = fmaxf(sqrtf(dp) - sqrtf(dn) + 1.f, 0.f);
}

extern "C" void kernel_launch(void* const* d_in, const int* in_sizes, int n_in,
                              void* d_out, int out_size, void* d_ws, size_t ws_size,
                              hipStream_t stream){
  const float* q    = (const float*)d_in[0];
  const float* keys = (const float*)d_in[1];
  float* out = (float*)d_out;
  float* ws  = (float*)d_ws;

  float*    score  = ws + WS_SCORE;
  float*    kT     = ws + WS_KEYST;
  unsigned* colmax = (unsigned*)(ws + WS_COLMAX);
  float*    colsum = ws + WS_COLSUM;
  float*    qu     = ws + WS_QU;
  int*      gidx   = (int*)(ws + WS_GIDX);
  int*      nidx   = (int*)(ws + WS_NIDX);

  hipLaunchKernelGGL(k_init,        dim3(65),  dim3(256), 0, stream, ws + WS_COLMAX, 16512);
  hipLaunchKernelGGL(k_transpose,   dim3(64),  dim3(256), 0, stream, keys, kT);
  hipLaunchKernelGGL(k_score,       dim3(256), dim3(256), 0, stream, q, kT, score, out + O_SM, gidx, nidx);
  hipLaunchKernelGGL(k_colmax,      dim3(256), dim3(256), 0, stream, score, colmax);
  hipLaunchKernelGGL(k_colsum,      dim3(256), dim3(256), 0, stream, score, colmax, colsum);
  hipLaunchKernelGGL(k_sq_scatter,  dim3(256), dim3(256), 0, stream, score, colmax, colsum, gidx, q, out + O_SQ, qu);
  hipLaunchKernelGGL(k_upmem,       dim3(64),  dim3(256), 0, stream, qu, keys, out + O_UM);
  hipLaunchKernelGGL(k_concat,      dim3(256), dim3(256), 0, stream, out + O_SM, kT, out + O_UQ);
  hipLaunchKernelGGL(k_copy_gather, dim3(256), dim3(256), 0, stream, q, keys, gidx, nidx,
                     out + O_UQ, out + O_SPR, out + O_GL);
}

// Round 2
// 786.668 us; speedup vs baseline: 3.4354x; 3.4354x over previous
//
#include <hip/hip_runtime.h>

// Problem: DIMS=256, T=1024, N=64 -> ROWS=65536 ; M=64 memory slots.
// query:  (256, 1024, 64) fp32  -> qr[row,d] = query[d*65536 + row]
// keys:   (64, 256) fp32
// Outputs (concat, fp32):
//  out0 updated_query (512,1024,64) : c<256 -> copy of query ; c>=256 -> (score_memory@keys)^T
//  out1 updated_memory (64,256)
//  out2 score_query   (65536,64)
//  out3 score_memory  (65536,64)
//  out4 spreading_loss(65536,)
//  out5 gathering_loss(65536,256)

#define ROWS 65536
#define EPS_T 1e-6f

// workspace layout (float offsets)
#define WS_SCORE   0          // 65536*64 ; later overlaid by scatter partials (exact same size)
#define WS_KEYST   4194304    // 256*64 (keys transposed, [d][m])
#define WS_COLMAX  4210688    // 64 (monotone-uint mapped)
#define WS_COLSUM  4210752    // 64
#define WS_GIDX    4210816    // 65536 int
#define WS_NIDX    4276352    // 65536 int

// output layout (float offsets)
#define O_UQ   0
#define O_UM   33554432
#define O_SQ   33570816
#define O_SM   37765120
#define O_SPR  41959424
#define O_GL   42024960

__device__ __forceinline__ unsigned fmap(float v){
  unsigned b = __float_as_uint(v);
  return (b & 0x80000000u) ? ~b : (b | 0x80000000u);   // order-preserving float->uint
}
__device__ __forceinline__ float funmap(unsigned u){
  unsigned b = (u & 0x80000000u) ? (u ^ 0x80000000u) : ~u;
  return __uint_as_float(b);
}

__global__ void k_init(float* p, int n){
  int i = blockIdx.x*256 + threadIdx.x;
  if (i < n) p[i] = 0.f;           // zero bits == 0u sentinel for colmax (-inf under fmap)
}

// keysT[d*64+m] = keys[m*256+d]
__global__ void k_transpose(const float* __restrict__ keys, float* __restrict__ kT){
  int idx = blockIdx.x*256 + threadIdx.x;
  int g = idx & 63, d = idx >> 6;
  kT[d*64 + g] = keys[g*256 + d];
}

// One thread per row: full 64-wide score row in registers.
// Writes raw score (ws), score_memory (out3), top-2 indices.
__global__ void __launch_bounds__(256) k_score(const float* __restrict__ q,
        const float* __restrict__ kT, float* __restrict__ score,
        float* __restrict__ out_sm, int* __restrict__ gidx, int* __restrict__ nidx){
  int r = blockIdx.x*256 + threadIdx.x;
  float acc[64];
  #pragma unroll
  for (int m=0;m<64;m++) acc[m]=0.f;
  #pragma unroll 2
  for (int d=0; d<256; d++){
    float qv = q[(size_t)d*ROWS + r];        // coalesced (lane = r)
    const float* kc = kT + d*64;             // wave-uniform -> scalar loads
    #pragma unroll
    for (int m=0;m<64;m++) acc[m] = fmaf(qv, kc[m], acc[m]);
  }
  // top-2 (first index wins on ties, matching lax.top_k)
  float v1=-3.4e38f, v2=-3.4e38f; int i1=0, i2=0;
  #pragma unroll
  for (int m=0;m<64;m++){
    float v=acc[m];
    if (v > v1){ v2=v1; i2=i1; v1=v; i1=m; }
    else if (v > v2){ v2=v; i2=m; }
  }
  gidx[r]=i1; nidx[r]=i2;
  float4* sp = (float4*)(score + (size_t)r*64);
  #pragma unroll
  for (int t=0;t<16;t++) sp[t] = make_float4(acc[4*t],acc[4*t+1],acc[4*t+2],acc[4*t+3]);
  // row softmax
  float s=0.f;
  #pragma unroll
  for (int m=0;m<64;m++){ acc[m]=__expf(acc[m]-v1); s+=acc[m]; }
  float inv = 1.f/s;
  float4* mp = (float4*)(out_sm + (size_t)r*64);
  #pragma unroll
  for (int t=0;t<16;t++) mp[t]=make_float4(acc[4*t]*inv,acc[4*t+1]*inv,acc[4*t+2]*inv,acc[4*t+3]*inv);
}

// column max over 65536 rows (pass 1 of column softmax)
__global__ void k_colmax(const float* __restrict__ score, unsigned* __restrict__ colmax){
  __shared__ float red[256];
  int m = threadIdx.x & 63, sub = threadIdx.x >> 6;
  int r0 = blockIdx.x*256 + sub*64;
  float v = -3.4e38f;
  for (int i=0;i<64;i++) v = fmaxf(v, score[(size_t)(r0+i)*64 + m]);
  red[threadIdx.x]=v; __syncthreads();
  if (threadIdx.x < 64){
    float a = fmaxf(fmaxf(red[m],red[64+m]),fmaxf(red[128+m],red[192+m]));
    atomicMax(&colmax[m], fmap(a));
  }
}

// column sum of exp (pass 2)
__global__ void k_colsum(const float* __restrict__ score, const unsigned* __restrict__ colmax,
                         float* __restrict__ colsum){
  __shared__ float red[256];
  int m = threadIdx.x & 63, sub = threadIdx.x >> 6;
  int r0 = blockIdx.x*256 + sub*64;
  float cm = funmap(colmax[m]);
  float v=0.f;
  for (int i=0;i<64;i++) v += __expf(score[(size_t)(r0+i)*64 + m] - cm);
  red[threadIdx.x]=v; __syncthreads();
  if (threadIdx.x<64){
    atomicAdd(&colsum[m], red[m]+red[64+m]+red[128+m]+red[192+m]);
  }
}

// score_query output only (weights now recomputed inside k_scatter)
__global__ void __launch_bounds__(256) k_sq(const float* __restrict__ score,
        const unsigned* __restrict__ colmax, const float* __restrict__ colsum,
        float* __restrict__ out_sq){
  int r = blockIdx.x*256 + threadIdx.x;
  const float4* sp = (const float4*)(score + (size_t)r*64);
  float4* op = (float4*)(out_sq + (size_t)r*64);
  #pragma unroll
  for (int t=0;t<16;t++){
    float4 v = sp[t], o;
    #pragma unroll
    for (int j=0;j<4;j++){
      int m = 4*t+j;
      (&o.x)[j] = __expf((&v.x)[j] - funmap(colmax[m])) / colsum[m];
    }
    op[t]=o;
  }
}

// Split-K one-hot GEMM: part[blk][g][d] = sum_{r in blk} w_r * 1[g==g_r] * q[d][r]
// 128 threads; thread t owns output column d = d_base + t (two 128-d halves).
// acc in LDS, XOR-swizzled; each thread owns its acc row exclusively -> no races.
// part overlays the score region: block blk's 16384-float slice == its own score rows,
// which it finishes reading (w gather, half 0 only) before the half-0 flush.
__global__ void __launch_bounds__(128) k_scatter(const float* __restrict__ q,
        const float* __restrict__ score_r, const unsigned* __restrict__ colmax,
        const int* __restrict__ gidx, float* __restrict__ part){
  __shared__ float acc[128*64];   // 32 KB
  __shared__ float qt[32*129];    // 16.5 KB, +1-pad transpose tile
  __shared__ float wl[256];
  __shared__ int   gl[256];
  const int t   = threadIdx.x;
  const int blk = blockIdx.x;
  const int r0b = blk*256;
  const int r_in = t & 31, dg = t >> 5;
  for (int half=0; half<2; half++){
    const int d_base = half*128;
    for (int i=t;i<8192;i+=128) acc[i]=0.f;
    for (int rt=0; rt<8; rt++){
      const int r0 = r0b + rt*32;
      if (half==0 && t<32){
        int r = r0 + t;
        int g = gidx[r];
        gl[rt*32+t] = g;
        wl[rt*32+t] = __expf(score_r[(size_t)r*64 + g] - funmap(colmax[g]));
      }
      // stage 32 rows x 128 d, coalesced along r (32-lane groups read 128B lines)
      #pragma unroll 8
      for (int i=0;i<32;i++){
        int d = dg + 4*i;
        qt[r_in*129 + d] = q[(size_t)(d_base+d)*ROWS + r0 + r_in];
      }
      __syncthreads();
      #pragma unroll 8
      for (int rr=0; rr<32; rr++){
        float wv = wl[rt*32+rr];          // broadcast
        int   g  = gl[rt*32+rr];          // broadcast
        float val = qt[rr*129 + t];       // 2-way bank alias (free)
        atomicAdd(&acc[t*64 + (g ^ (t & 31))], wv*val);  // ds_add_f32, thread-private row
      }
      __syncthreads();
    }
    float* dst = part + (size_t)blk*16384 + d_base + t;
    for (int g=0; g<64; g++)
      dst[(size_t)g*256] = acc[t*64 + (g ^ (t & 31))];
    __syncthreads();
  }
}

// reduce 256 partials + fused updated_memory = l2norm(query_update + keys)
__global__ void __launch_bounds__(256) k_qured_upmem(const float* __restrict__ part,
        const float* __restrict__ keys, float* __restrict__ out_um){
  __shared__ float red[4];
  int g = blockIdx.x, t = threadIdx.x;
  float s = 0.f;
  const float* p = part + (size_t)g*256 + t;
  #pragma unroll 4
  for (int b=0;b<256;b++) s += p[(size_t)b*16384];
  float x = s + keys[g*256+t];
  float ss = x*x;
  #pragma unroll
  for (int o=32;o>0;o>>=1) ss += __shfl_down(ss, o, 64);
  if ((t & 63)==0) red[t>>6]=ss;
  __syncthreads();
  float nrm = sqrtf(red[0]+red[1]+red[2]+red[3]);
  out_um[g*256+t] = x / fmaxf(nrm, 1e-12f);
}

// second half of updated_query: (score_memory @ keys) stored channel-major
__global__ void __launch_bounds__(256) k_concat(const float* __restrict__ sm,
        const float* __restrict__ kT, float* __restrict__ out_uq){
  int r = blockIdx.x*256 + threadIdx.x;
  float v[64];
  const float4* sp = (const float4*)(sm + (size_t)r*64);
  #pragma unroll
  for (int t=0;t<16;t++){ float4 x=sp[t]; v[4*t]=x.x; v[4*t+1]=x.y; v[4*t+2]=x.z; v[4*t+3]=x.w; }
  float* dst = out_uq + (size_t)256*ROWS + r;
  #pragma unroll 2
  for (int d=0; d<256; d++){
    const float* kc = kT + d*64;    // uniform -> scalar
    float a=0.f;
    #pragma unroll
    for (int m=0;m<64;m++) a = fmaf(v[m], kc[m], a);
    dst[(size_t)d*ROWS] = a;        // coalesced
  }
}

// query copy into out0 + gathering_loss + spreading_loss
__global__ void __launch_bounds__(256) k_copy_gather(const float* __restrict__ q,
        const float* __restrict__ keys, const int* __restrict__ gidx, const int* __restrict__ nidx,
        float* __restrict__ out_uq, float* __restrict__ out_spr, float* __restrict__ out_gl){
  __shared__ float KT[256*64];      // KT[d][g]
  for (int idx=threadIdx.x; idx<16384; idx+=256){
    int g = idx & 63, d = idx >> 6;
    KT[d*64+g] = keys[g*256+d];
  }
  __syncthreads();
  int r = blockIdx.x*256 + threadIdx.x;
  int g = gidx[r], n2 = nidx[r];
  float dp=0.f, dn=0.f;
  for (int d0=0; d0<256; d0+=4){
    float4 gl;
    #pragma unroll
    for (int i=0;i<4;i++){
      int d=d0+i;
      float qv = q[(size_t)d*ROWS + r];
      out_uq[(size_t)d*ROWS + r] = qv;          // first-half copy
      float kp = KT[d*64+g];
      float kn = KT[d*64+n2];
      float cp = qv - kp, cn = qv - kn;
      (&gl.x)[i] = cp*cp;
      float a = cp + EPS_T, b = cn + EPS_T;
      dp = fmaf(a,a,dp); dn = fmaf(b,b,dn);
    }
    *(float4*)(out_gl + (size_t)r*256 + d0) = gl;
  }
  out_spr[r] = fmaxf(sqrtf(dp) - sqrtf(dn) + 1.f, 0.f);
}

extern "C" void kernel_launch(void* const* d_in, const int* in_sizes, int n_in,
                              void* d_out, int out_size, void* d_ws, size_t ws_size,
                              hipStream_t stream){
  const float* q    = (const float*)d_in[0];
  const float* keys = (const float*)d_in[1];
  float* out = (float*)d_out;
  float* ws  = (float*)d_ws;

  float*    score  = ws + WS_SCORE;
  float*    kT     = ws + WS_KEYST;
  unsigned* colmax = (unsigned*)(ws + WS_COLMAX);
  float*    colsum = ws + WS_COLSUM;
  int*      gidx   = (int*)(ws + WS_GIDX);
  int*      nidx   = (int*)(ws + WS_NIDX);

  hipLaunchKernelGGL(k_init,        dim3(1),   dim3(256), 0, stream, ws + WS_COLMAX, 128);
  hipLaunchKernelGGL(k_transpose,   dim3(64),  dim3(256), 0, stream, keys, kT);
  hipLaunchKernelGGL(k_score,       dim3(256), dim3(256), 0, stream, q, kT, score, out + O_SM, gidx, nidx);
  hipLaunchKernelGGL(k_colmax,      dim3(256), dim3(256), 0, stream, score, colmax);
  hipLaunchKernelGGL(k_colsum,      dim3(256), dim3(256), 0, stream, score, colmax, colsum);
  hipLaunchKernelGGL(k_sq,          dim3(256), dim3(256), 0, stream, score, colmax, colsum, out + O_SQ);
  hipLaunchKernelGGL(k_scatter,     dim3(256), dim3(128), 0, stream, q, score, colmax, gidx, score /*part overlay*/);
  hipLaunchKernelGGL(k_qured_upmem, dim3(64),  dim3(256), 0, stream, score /*part*/, keys, out + O_UM);
  hipLaunchKernelGGL(k_concat,      dim3(256), dim3(256), 0, stream, out + O_SM, kT, out + O_UQ);
  hipLaunchKernelGGL(k_copy_gather, dim3(256), dim3(256), 0, stream, q, keys, gidx, nidx,
                     out + O_UQ, out + O_SPR, out + O_GL);
}